// Round 1
// baseline (369.461 us; speedup 1.0000x reference)
//
#include <hip/hip_runtime.h>
#include <hip/hip_bf16.h>

typedef __attribute__((ext_vector_type(8))) short bf16x8;
typedef __attribute__((ext_vector_type(4))) short s16x4;
typedef __attribute__((ext_vector_type(4))) float f32x4;
typedef __attribute__((ext_vector_type(4))) int   i32x4;

__device__ inline short f2bf(float f){
  union { float f; unsigned u; } v; v.f = f;
  unsigned r = v.u + 0x7fffu + ((v.u >> 16) & 1u);   // RNE
  return (short)(r >> 16);
}

// ---------- prep: f32 -> bf16 convert (vectorized) ----------
__global__ __launch_bounds__(256) void k_cvt(const float* __restrict__ in, short* __restrict__ out, int n4){
  int i = blockIdx.x * 256 + threadIdx.x;
  if (i < n4){
    float4 v = reinterpret_cast<const float4*>(in)[i];
    s16x4 o;
    o[0] = f2bf(v.x); o[1] = f2bf(v.y); o[2] = f2bf(v.z); o[3] = f2bf(v.w);
    reinterpret_cast<s16x4*>(out)[i] = o;
  }
}

// ---------- prep: Qt[h][j][i] = Q[h][i][j], bf16 ----------
__global__ __launch_bounds__(256) void k_qt(const float* __restrict__ Q, short* __restrict__ Qt){
  __shared__ float t[32][33];
  int bid = blockIdx.x;
  int h = bid >> 6, tj = (bid >> 3) & 7, ti = bid & 7;
  const float* q = Q + h * 65536;
  short* o = Qt + h * 65536;
  int tx = threadIdx.x & 31, ty = threadIdx.x >> 5;
#pragma unroll
  for (int rr = 0; rr < 4; rr++)
    t[ty + rr*8][tx] = q[(ti*32 + ty + rr*8)*256 + tj*32 + tx];
  __syncthreads();
#pragma unroll
  for (int rr = 0; rr < 4; rr++)
    o[(tj*32 + ty + rr*8)*256 + ti*32 + tx] = f2bf(t[tx][ty + rr*8]);
}

// ---------- phase 1: C[m][n] = sum_k A[m][k]*B[n][k], bf16 out ----------
// MODE 0 (qs): A=S_b[1024x256], B=Qt_h[256x256], C=qs[bh][t][j] ldc=256
// MODE 1 (es): A=E_h[256x256],  B=S_b[1024x256], C=es_t[bh][i][u] ldc=1024
template<int MODE>
__global__ __launch_bounds__(256) void k_gemm(const short* __restrict__ S, const short* __restrict__ W, short* __restrict__ C){
  __shared__ short At[128*64];
  __shared__ short Bt[128*64];
  int bh = blockIdx.y, b = bh >> 3, h = bh & 7;
  const short* A; const short* Bm; short* Co; int ldc, mt, nt;
  if (MODE == 0){
    A = S + b*262144; Bm = W + h*65536; Co = C + bh*262144; ldc = 256;
    mt = blockIdx.x >> 1; nt = blockIdx.x & 1;
  } else {
    A = W + h*65536; Bm = S + b*262144; Co = C + bh*262144; ldc = 1024;
    mt = blockIdx.x >> 3; nt = blockIdx.x & 7;
  }
  int Mb = mt*128, Nb = nt*128;
  int tid = threadIdx.x, lane = tid & 63, wv = tid >> 6;
  int wm = wv >> 1, wn = wv & 1;
  int g = lane >> 4, r16 = lane & 15;
  f32x4 acc[4][4] = {};
  for (int kk = 0; kk < 4; kk++){
    __syncthreads();
    for (int c = tid; c < 1024; c += 256){
      int row = c >> 3, slot = c & 7;
      int ss = slot ^ (row & 7);
      *reinterpret_cast<i32x4*>(At + row*64 + ss*8) =
        *reinterpret_cast<const i32x4*>(A + (Mb+row)*256 + kk*64 + slot*8);
      *reinterpret_cast<i32x4*>(Bt + row*64 + ss*8) =
        *reinterpret_cast<const i32x4*>(Bm + (Nb+row)*256 + kk*64 + slot*8);
    }
    __syncthreads();
#pragma unroll
    for (int ks = 0; ks < 2; ks++){
      int slot = ks*4 + g;
      bf16x8 af[4], bf_[4];
#pragma unroll
      for (int fm = 0; fm < 4; fm++){
        int row = wm*64 + fm*16 + r16;
        af[fm] = *reinterpret_cast<const bf16x8*>(At + row*64 + (slot ^ (row & 7))*8);
      }
#pragma unroll
      for (int fn = 0; fn < 4; fn++){
        int row = wn*64 + fn*16 + r16;
        bf_[fn] = *reinterpret_cast<const bf16x8*>(Bt + row*64 + (slot ^ (row & 7))*8);
      }
#pragma unroll
      for (int fm = 0; fm < 4; fm++)
#pragma unroll
        for (int fn = 0; fn < 4; fn++)
          acc[fm][fn] = __builtin_amdgcn_mfma_f32_16x16x32_bf16(af[fm], bf_[fn], acc[fm][fn], 0, 0, 0);
    }
  }
#pragma unroll
  for (int fm = 0; fm < 4; fm++)
#pragma unroll
    for (int fn = 0; fn < 4; fn++)
#pragma unroll
      for (int rg = 0; rg < 4; rg++){
        int m = Mb + wm*64 + fm*16 + g*4 + rg;
        int n = Nb + wn*64 + fn*16 + r16;
        Co[m*ldc + n] = f2bf(acc[fm][fn][rg]);
      }
}

// ---------- phase 2: r[b,t,i] += sum_h sum_{u<=t} Omega * es ----------
// grid 256: b(8) x pair(8) x hg(4); block = 4 waves, BT=64 (16 t-rows/wave), BU=32
__global__ __launch_bounds__(256) void k_attn(const short* __restrict__ S16, const short* __restrict__ qs,
                                              const short* __restrict__ est, float* __restrict__ out){
  __shared__ short qt[64*256];   // qs tile [t][j], swizzled 16B-slot ^ (row&7)
  __shared__ short st[32*256];   // S_u tile [u][j], swizzled
  __shared__ short el[256*32];   // es_t tile [i][u], swizzled
  int bI = blockIdx.x >> 5, p = (blockIdx.x >> 2) & 7, hg = blockIdx.x & 3;
  int tid = threadIdx.x, lane = tid & 63, w = tid >> 6;
  int g = lane >> 4, r16 = lane & 15;
  const short* Sb = S16 + bI * 262144;

  for (int pass = 0; pass < 2; pass++){
    int T = pass ? (15 - p) : p;       // pair (p, 15-p): uniform triangular work
    int t_lane = T*64 + w*16 + r16;    // Omega^T column owned by this lane
    f32x4 racc[16] = {};
    for (int hh = 0; hh < 2; hh++){
      int h = hg*2 + hh;
      const short* qsp = qs + ((bI*8 + h)*1024 + T*64) * 256;
      const short* esp = est + (bI*8 + h) * 262144;
      __syncthreads();
      for (int c = tid; c < 2048; c += 256){
        int row = c >> 5, slot = c & 31;
        i32x4 v = *reinterpret_cast<const i32x4*>(qsp + row*256 + slot*8);
        *reinterpret_cast<i32x4*>(qt + row*256 + (slot ^ (row & 7))*8) = v;
      }
      int nut = 2*T + 2;
      for (int ut = 0; ut < nut; ut++){
        __syncthreads();
        for (int c = tid; c < 1024; c += 256){
          int row = c >> 5, slot = c & 31;
          i32x4 v = *reinterpret_cast<const i32x4*>(Sb + (ut*32 + row)*256 + slot*8);
          *reinterpret_cast<i32x4*>(st + row*256 + (slot ^ (row & 7))*8) = v;
        }
        for (int c = tid; c < 2048; c += 256){
          int row = c >> 3, slot = c & 7;
          s16x4 v = *reinterpret_cast<const s16x4*>(esp + row*1024 + ut*32 + slot*4);
          *reinterpret_cast<s16x4*>(el + row*32 + (slot ^ (row & 7))*4) = v;
        }
        __syncthreads();
        // Omega^T[u][t] = sum_j S_u[u][j] * qs[t][j]
        f32x4 om[2] = {};
        int trow = w*16 + r16;
#pragma unroll
        for (int ks = 0; ks < 8; ks++){
          int slot = ks*4 + g;
          bf16x8 bq = *reinterpret_cast<const bf16x8*>(qt + trow*256 + (slot ^ (trow & 7))*8);
#pragma unroll
          for (int q = 0; q < 2; q++){
            int urow = q*16 + r16;
            bf16x8 as = *reinterpret_cast<const bf16x8*>(st + urow*256 + (slot ^ (urow & 7))*8);
            om[q] = __builtin_amdgcn_mfma_f32_16x16x32_bf16(as, bq, om[q], 0, 0, 0);
          }
        }
        // mask (lane-local) + repack to PV A-fragment via K-permutation trick:
        // k_mine(g,jj) = (jj>>2)*16 + g*4 + (jj&3)
        int ub = ut*32;
        bf16x8 PA;
#pragma unroll
        for (int q = 0; q < 2; q++)
#pragma unroll
          for (int rg = 0; rg < 4; rg++){
            int u = ub + q*16 + g*4 + rg;
            float v = (u <= t_lane) ? om[q][rg] : 0.0f;
            PA[q*4 + rg] = f2bf(v);
          }
        // racc[n] += Omega(16t x 32u) * es(32u x 256i), B read with same k_mine
#pragma unroll
        for (int n = 0; n < 16; n++){
          int irow = n*16 + r16;
          s16x4 lo = *reinterpret_cast<const s16x4*>(el + irow*32 + ((g       ^ (irow & 7)))*4);
          s16x4 hi = *reinterpret_cast<const s16x4*>(el + irow*32 + (((4 + g) ^ (irow & 7)))*4);
          bf16x8 be;
          be[0]=lo[0]; be[1]=lo[1]; be[2]=lo[2]; be[3]=lo[3];
          be[4]=hi[0]; be[5]=hi[1]; be[6]=hi[2]; be[7]=hi[3];
          racc[n] = __builtin_amdgcn_mfma_f32_16x16x32_bf16(PA, be, racc[n], 0, 0, 0);
        }
      }
    }
    float* ob = out + bI*262144;
#pragma unroll
    for (int n = 0; n < 16; n++)
#pragma unroll
      for (int rg = 0; rg < 4; rg++){
        int tO = T*64 + w*16 + g*4 + rg;
        atomicAdd(&ob[tO*256 + n*16 + r16], racc[n][rg]);
      }
  }
}

extern "C" void kernel_launch(void* const* d_in, const int* in_sizes, int n_in,
                              void* d_out, int out_size, void* d_ws, size_t ws_size,
                              hipStream_t stream){
  (void)in_sizes; (void)n_in; (void)out_size; (void)ws_size;
  const float* s = (const float*)d_in[0];
  const float* Q = (const float*)d_in[1];
  const float* E = (const float*)d_in[2];
  float* out = (float*)d_out;
  char* ws = (char*)d_ws;
  // ws layout (bytes): S16 4MB | E16 1MB | Qt 1MB | qs 32MB | es_t 32MB  (~70MB total)
  short* S16 = (short*)(ws);
  short* E16 = (short*)(ws + 4194304);
  short* Qt  = (short*)(ws + 5242880);
  short* qsb = (short*)(ws + 6291456);
  short* est = (short*)(ws + 39845888);

  hipMemsetAsync(out, 0, (size_t)8*1024*256*sizeof(float), stream);
  k_cvt<<<2048, 256, 0, stream>>>(s, S16, 524288);   // s: 2,097,152 elems / 4
  k_cvt<<<512,  256, 0, stream>>>(E, E16, 131072);   // E: 524,288 elems / 4
  k_qt <<<512,  256, 0, stream>>>(Q, Qt);
  k_gemm<0><<<dim3(16, 64), 256, 0, stream>>>(S16, Qt,  qsb);
  k_gemm<1><<<dim3(16, 64), 256, 0, stream>>>(S16, E16, est);
  k_attn<<<256, 256, 0, stream>>>(S16, qsb, est, out);
}

// Round 2
// 205.600 us; speedup vs baseline: 1.7970x; 1.7970x over previous
//
#include <hip/hip_runtime.h>
#include <hip/hip_bf16.h>

typedef __attribute__((ext_vector_type(8))) short bf16x8;
typedef __attribute__((ext_vector_type(4))) short s16x4;
typedef __attribute__((ext_vector_type(4))) float f32x4;
typedef __attribute__((ext_vector_type(4))) int   i32x4;

__device__ inline short f2bf(float f){
  union { float f; unsigned u; } v; v.f = f;
  unsigned r = v.u + 0x7fffu + ((v.u >> 16) & 1u);   // RNE
  return (short)(r >> 16);
}

// ---------- prep: E f32 -> bf16 linear ----------
__global__ __launch_bounds__(256) void k_cvt(const float* __restrict__ in, short* __restrict__ out, int n4){
  int i = blockIdx.x * 256 + threadIdx.x;
  if (i < n4){
    float4 v = reinterpret_cast<const float4*>(in)[i];
    s16x4 o;
    o[0] = f2bf(v.x); o[1] = f2bf(v.y); o[2] = f2bf(v.z); o[3] = f2bf(v.w);
    reinterpret_cast<s16x4*>(out)[i] = o;
  }
}

// ---------- prep: s -> bf16, linear copy AND swizzled/u-chunked copy ----------
// swz layout: [b][t>>5][t&31][ ((j>>3)^(t&7))<<3 | j&7 ]
__global__ __launch_bounds__(256) void k_cvt_s(const float* __restrict__ in, short* __restrict__ lin, short* __restrict__ swz){
  int i = blockIdx.x * 256 + threadIdx.x;      // 262144 groups of 8 elems
  int e = i * 8;
  float4 v0 = reinterpret_cast<const float4*>(in)[i*2];
  float4 v1 = reinterpret_cast<const float4*>(in)[i*2 + 1];
  bf16x8 o;
  o[0]=f2bf(v0.x); o[1]=f2bf(v0.y); o[2]=f2bf(v0.z); o[3]=f2bf(v0.w);
  o[4]=f2bf(v1.x); o[5]=f2bf(v1.y); o[6]=f2bf(v1.z); o[7]=f2bf(v1.w);
  *reinterpret_cast<bf16x8*>(lin + e) = o;
  int b = e >> 18, t = (e >> 8) & 1023, j = e & 255;
  int slot = j >> 3;
  size_t off = (size_t)b*262144 + (t>>5)*8192 + (t&31)*256 + ((slot ^ (t&7)) << 3);
  *reinterpret_cast<bf16x8*>(swz + off) = o;
}

// ---------- prep: Qt[h][j][i] = Q[h][i][j], bf16 ----------
__global__ __launch_bounds__(256) void k_qt(const float* __restrict__ Q, short* __restrict__ Qt){
  __shared__ float t[32][33];
  int bid = blockIdx.x;
  int h = bid >> 6, tj = (bid >> 3) & 7, ti = bid & 7;
  const float* q = Q + h * 65536;
  short* o = Qt + h * 65536;
  int tx = threadIdx.x & 31, ty = threadIdx.x >> 5;
#pragma unroll
  for (int rr = 0; rr < 4; rr++)
    t[ty + rr*8][tx] = q[(ti*32 + ty + rr*8)*256 + tj*32 + tx];
  __syncthreads();
#pragma unroll
  for (int rr = 0; rr < 4; rr++)
    o[(tj*32 + ty + rr*8)*256 + ti*32 + tx] = f2bf(t[tx][ty + rr*8]);
}

// ---------- phase 1: C[m][n] = sum_k A[m][k]*B[n][k], bf16 out, swizzled layouts ----------
// MODE 0 (qs): A=S_b[1024x256], B=Qt_h[256x256] -> qs[bh][t][swz(j)]
// MODE 1 (es): A=E_h[256x256],  B=S_b[1024x256] -> est[bh][u>>5][i][swz(u&31)]
template<int MODE>
__global__ __launch_bounds__(256) void k_gemm(const short* __restrict__ S, const short* __restrict__ W, short* __restrict__ C){
  __shared__ short At[128*64];
  __shared__ short Bt[128*64];
  int bh = blockIdx.y, b = bh >> 3, h = bh & 7;
  const short* A; const short* Bm; short* Co; int mt, nt;
  if (MODE == 0){
    A = S + b*262144; Bm = W + h*65536; Co = C + (size_t)bh*262144;
    mt = blockIdx.x >> 1; nt = blockIdx.x & 1;
  } else {
    A = W + h*65536; Bm = S + b*262144; Co = C + (size_t)bh*262144;
    mt = blockIdx.x >> 3; nt = blockIdx.x & 7;
  }
  int Mb = mt*128, Nb = nt*128;
  int tid = threadIdx.x, lane = tid & 63, wv = tid >> 6;
  int wm = wv >> 1, wn = wv & 1;
  int g = lane >> 4, r16 = lane & 15;
  f32x4 acc[4][4] = {};
  for (int kk = 0; kk < 4; kk++){
    __syncthreads();
    for (int c = tid; c < 1024; c += 256){
      int row = c >> 3, slot = c & 7;
      int ss = slot ^ (row & 7);
      *reinterpret_cast<i32x4*>(At + row*64 + ss*8) =
        *reinterpret_cast<const i32x4*>(A + (Mb+row)*256 + kk*64 + slot*8);
      *reinterpret_cast<i32x4*>(Bt + row*64 + ss*8) =
        *reinterpret_cast<const i32x4*>(Bm + (Nb+row)*256 + kk*64 + slot*8);
    }
    __syncthreads();
#pragma unroll
    for (int ks = 0; ks < 2; ks++){
      int slot = ks*4 + g;
      bf16x8 af[4], bf_[4];
#pragma unroll
      for (int fm = 0; fm < 4; fm++){
        int row = wm*64 + fm*16 + r16;
        af[fm] = *reinterpret_cast<const bf16x8*>(At + row*64 + (slot ^ (row & 7))*8);
      }
#pragma unroll
      for (int fn = 0; fn < 4; fn++){
        int row = wn*64 + fn*16 + r16;
        bf_[fn] = *reinterpret_cast<const bf16x8*>(Bt + row*64 + (slot ^ (row & 7))*8);
      }
#pragma unroll
      for (int fm = 0; fm < 4; fm++)
#pragma unroll
        for (int fn = 0; fn < 4; fn++)
          acc[fm][fn] = __builtin_amdgcn_mfma_f32_16x16x32_bf16(af[fm], bf_[fn], acc[fm][fn], 0, 0, 0);
    }
  }
#pragma unroll
  for (int fm = 0; fm < 4; fm++)
#pragma unroll
    for (int fn = 0; fn < 4; fn++)
#pragma unroll
      for (int rg = 0; rg < 4; rg++){
        int m = Mb + wm*64 + fm*16 + g*4 + rg;
        int n = Nb + wn*64 + fn*16 + r16;
        if (MODE == 0){
          // qs[t][swz(j)]
          Co[m*256 + (((n>>3) ^ (m&7)) << 3) + (n&7)] = f2bf(acc[fm][fn][rg]);
        } else {
          // est[u>>5][i][swz(u&31)]
          Co[(n>>5)*8192 + m*32 + ((((n>>2)&7) ^ (m&7)) << 2) + (n&3)] = f2bf(acc[fm][fn][rg]);
        }
      }
}

// ---------- phase 2: r[b,t,i] += sum_{u<=t} Omega * es ----------
// grid 512: b(8) x pair(8) x h(8); block = 4 waves, BT=64 (16 t-rows/wave), BU=32
__global__ __launch_bounds__(256, 2) void k_attn(const short* __restrict__ Ss, const short* __restrict__ qs,
                                                 const short* __restrict__ est, float* __restrict__ out){
  __shared__ short qt[64*256];   // 32KB, pre-swizzled
  __shared__ short st[32*256];   // 16KB, pre-swizzled
  __shared__ short el[256*32];   // 16KB, pre-swizzled
  int bI = blockIdx.x >> 6, p = (blockIdx.x >> 3) & 7, h = blockIdx.x & 7;
  int tid = threadIdx.x, lane = tid & 63, w = tid >> 6;
  int g = lane >> 4, r16 = lane & 15;
  int bh = bI*8 + h;
  const short* Sbs = Ss + (size_t)bI * 262144;
  const short* esb = est + (size_t)bh * 262144;

  for (int pass = 0; pass < 2; pass++){
    int T = pass ? (15 - p) : p;       // pair (p, 15-p): uniform work (36 iters/block)
    int t_lane = T*64 + w*16 + r16;
    const short* qsp = qs + ((size_t)bh*1024 + T*64) * 256;
    f32x4 racc[16] = {};
    __syncthreads();                   // prev-pass LDS reads done
#pragma unroll
    for (int k = 0; k < 8; k++){
      int c = tid + k*256;
      *reinterpret_cast<i32x4*>(qt + c*8) = *reinterpret_cast<const i32x4*>(qsp + c*8);
    }
    int nut = 2*T + 2;
    i32x4 pst[4], pel[4];
#pragma unroll
    for (int k = 0; k < 4; k++){
      int c = (tid + k*256) * 8;
      pst[k] = *reinterpret_cast<const i32x4*>(Sbs + c);
      pel[k] = *reinterpret_cast<const i32x4*>(esb + c);
    }
    for (int ut = 0; ut < nut; ut++){
      // commit current tile to LDS (linear, coalesced)
#pragma unroll
      for (int k = 0; k < 4; k++){
        int c = (tid + k*256) * 8;
        *reinterpret_cast<i32x4*>(st + c) = pst[k];
        *reinterpret_cast<i32x4*>(el + c) = pel[k];
      }
      // issue next-tile loads (in flight across the MFMA phase)
      if (ut + 1 < nut){
        const short* s_src = Sbs + (size_t)(ut+1)*8192;
        const short* e_src = esb + (size_t)(ut+1)*8192;
#pragma unroll
        for (int k = 0; k < 4; k++){
          int c = (tid + k*256) * 8;
          pst[k] = *reinterpret_cast<const i32x4*>(s_src + c);
          pel[k] = *reinterpret_cast<const i32x4*>(e_src + c);
        }
      }
      __syncthreads();
      // Omega^T[u][t] = sum_j S_u[u][j] * qs[t][j]
      f32x4 om[2] = {};
      int trow = w*16 + r16;
      __builtin_amdgcn_s_setprio(1);
#pragma unroll
      for (int ks = 0; ks < 8; ks++){
        int slot = ks*4 + g;
        bf16x8 bq = *reinterpret_cast<const bf16x8*>(qt + trow*256 + (slot ^ (trow & 7))*8);
#pragma unroll
        for (int q = 0; q < 2; q++){
          int urow = q*16 + r16;
          bf16x8 as = *reinterpret_cast<const bf16x8*>(st + urow*256 + (slot ^ (urow & 7))*8);
          om[q] = __builtin_amdgcn_mfma_f32_16x16x32_bf16(as, bq, om[q], 0, 0, 0);
        }
      }
      __builtin_amdgcn_s_setprio(0);
      // mask (lane-local) + repack to PV A-fragment via K-permutation trick
      int ub = ut*32;
      bf16x8 PA;
#pragma unroll
      for (int q = 0; q < 2; q++)
#pragma unroll
        for (int rg = 0; rg < 4; rg++){
          int u = ub + q*16 + g*4 + rg;
          float v = (u <= t_lane) ? om[q][rg] : 0.0f;
          PA[q*4 + rg] = f2bf(v);
        }
      // racc[n] += Omega(16t x 32u) * es(32u x 256i), B read with same k-permutation
      __builtin_amdgcn_s_setprio(1);
#pragma unroll
      for (int n = 0; n < 16; n++){
        int irow = n*16 + r16;
        s16x4 lo = *reinterpret_cast<const s16x4*>(el + irow*32 + ((g       ^ (irow & 7)))*4);
        s16x4 hi = *reinterpret_cast<const s16x4*>(el + irow*32 + (((4 + g) ^ (irow & 7)))*4);
        bf16x8 be;
        be[0]=lo[0]; be[1]=lo[1]; be[2]=lo[2]; be[3]=lo[3];
        be[4]=hi[0]; be[5]=hi[1]; be[6]=hi[2]; be[7]=hi[3];
        racc[n] = __builtin_amdgcn_mfma_f32_16x16x32_bf16(PA, be, racc[n], 0, 0, 0);
      }
      __builtin_amdgcn_s_setprio(0);
      __syncthreads();
    }
    float* ob = out + (size_t)bI*262144;
#pragma unroll
    for (int n = 0; n < 16; n++)
#pragma unroll
      for (int rg = 0; rg < 4; rg++){
        int tO = T*64 + w*16 + g*4 + rg;
        atomicAdd(&ob[tO*256 + n*16 + r16], racc[n][rg]);
      }
  }
}

extern "C" void kernel_launch(void* const* d_in, const int* in_sizes, int n_in,
                              void* d_out, int out_size, void* d_ws, size_t ws_size,
                              hipStream_t stream){
  (void)in_sizes; (void)n_in; (void)out_size; (void)ws_size;
  const float* s = (const float*)d_in[0];
  const float* Q = (const float*)d_in[1];
  const float* E = (const float*)d_in[2];
  float* out = (float*)d_out;
  char* ws = (char*)d_ws;
  // ws: S16 4MB | S16s 4MB | E16 1MB | Qt 1MB | qs 32MB | est 32MB  (~74MB)
  short* S16  = (short*)(ws);
  short* S16s = (short*)(ws + 4194304);
  short* E16  = (short*)(ws + 8388608);
  short* Qt   = (short*)(ws + 9437184);
  short* qsb  = (short*)(ws + 10485760);
  short* est  = (short*)(ws + 44040192);

  hipMemsetAsync(out, 0, (size_t)8*1024*256*sizeof(float), stream);
  k_cvt_s<<<1024, 256, 0, stream>>>(s, S16, S16s);
  k_cvt  <<<512,  256, 0, stream>>>(E, E16, 131072);
  k_qt   <<<512,  256, 0, stream>>>(Q, Qt);
  k_gemm<0><<<dim3(16, 64), 256, 0, stream>>>(S16, Qt,  qsb);
  k_gemm<1><<<dim3(16, 64), 256, 0, stream>>>(S16, E16, est);
  k_attn<<<512, 256, 0, stream>>>(S16s, qsb, est, out);
}

// Round 3
// 183.590 us; speedup vs baseline: 2.0124x; 1.1199x over previous
//
#include <hip/hip_runtime.h>
#include <hip/hip_bf16.h>

typedef __attribute__((ext_vector_type(8))) short bf16x8;
typedef __attribute__((ext_vector_type(4))) short s16x4;
typedef __attribute__((ext_vector_type(4))) float f32x4;
typedef __attribute__((ext_vector_type(4))) int   i32x4;
typedef unsigned int u32;

__device__ inline short f2bf(float f){
  union { float f; unsigned u; } v; v.f = f;
  unsigned r = v.u + 0x7fffu + ((v.u >> 16) & 1u);   // RNE
  return (short)(r >> 16);
}

__device__ __forceinline__ void gll16(const void* gp, void* lp){
  __builtin_amdgcn_global_load_lds((const __attribute__((address_space(1))) u32*)gp,
                                   (__attribute__((address_space(3))) u32*)lp, 16, 0, 0);
}

// ---------- prep: s -> S16 (linear bf16) + S16s ([b][uc][32][swz j]) ----------
__global__ __launch_bounds__(256) void k_cvt_s(const float* __restrict__ in, short* __restrict__ lin, short* __restrict__ swz){
  int i = blockIdx.x * 256 + threadIdx.x;      // 262144 groups of 8 elems
  int e = i * 8;
  float4 v0 = reinterpret_cast<const float4*>(in)[i*2];
  float4 v1 = reinterpret_cast<const float4*>(in)[i*2 + 1];
  bf16x8 o;
  o[0]=f2bf(v0.x); o[1]=f2bf(v0.y); o[2]=f2bf(v0.z); o[3]=f2bf(v0.w);
  o[4]=f2bf(v1.x); o[5]=f2bf(v1.y); o[6]=f2bf(v1.z); o[7]=f2bf(v1.w);
  *reinterpret_cast<bf16x8*>(lin + e) = o;
  int b = e >> 18, t = (e >> 8) & 1023, j = e & 255;
  int slot = j >> 3;
  size_t off = (size_t)b*262144 + (t>>5)*8192 + (t&31)*256 + ((slot ^ (t&7)) << 3);
  *reinterpret_cast<bf16x8*>(swz + off) = o;
}

// ---------- prep: Stc[b][uc][j][swz u'] = s[b][uc*32+u'][j] ----------
__global__ __launch_bounds__(256) void k_st(const float* __restrict__ s, short* __restrict__ Stc){
  __shared__ float t[32][257];
  int b = blockIdx.x >> 5, uc = blockIdx.x & 31;
  const float* sp = s + ((size_t)b*1024 + uc*32)*256;
  int tid = threadIdx.x;
#pragma unroll 8
  for (int r = 0; r < 32; r++) t[r][tid] = sp[r*256 + tid];
  __syncthreads();
  int j = tid;
  short* orow = Stc + (size_t)b*262144 + uc*8192 + j*32;
#pragma unroll
  for (int sl = 0; sl < 8; sl++){
    s16x4 v;
#pragma unroll
    for (int q = 0; q < 4; q++) v[q] = f2bf(t[sl*4+q][j]);
    *reinterpret_cast<s16x4*>(orow + ((sl ^ (j&7)) << 2)) = v;
  }
}

// ---------- prep: E -> bf16, pre-swizzled per 64-col block ----------
__global__ __launch_bounds__(256) void k_cvtE(const float* __restrict__ in, short* __restrict__ out){
  int i = blockIdx.x * 256 + threadIdx.x;   // 131072
  int e = i * 4;
  float4 v = reinterpret_cast<const float4*>(in)[i];
  s16x4 o;
  o[0]=f2bf(v.x); o[1]=f2bf(v.y); o[2]=f2bf(v.z); o[3]=f2bf(v.w);
  int hi = e >> 8, j = e & 255;
  int pos = (j>>6)*64 + ((((j>>3)&7) ^ (hi&7)) << 3) + (j&7);
  *reinterpret_cast<s16x4*>(out + hi*256 + pos) = o;
}

// ---------- prep: Qt[h][j][i] = Q[h][i][j], bf16 ----------
__global__ __launch_bounds__(256) void k_qt(const float* __restrict__ Q, short* __restrict__ Qt){
  __shared__ float t[32][33];
  int bid = blockIdx.x;
  int h = bid >> 6, tj = (bid >> 3) & 7, ti = bid & 7;
  const float* q = Q + h * 65536;
  short* o = Qt + h * 65536;
  int tx = threadIdx.x & 31, ty = threadIdx.x >> 5;
#pragma unroll
  for (int rr = 0; rr < 4; rr++)
    t[ty + rr*8][tx] = q[(ti*32 + ty + rr*8)*256 + tj*32 + tx];
  __syncthreads();
#pragma unroll
  for (int rr = 0; rr < 4; rr++)
    o[(tj*32 + ty + rr*8)*256 + ti*32 + tx] = f2bf(t[tx][ty + rr*8]);
}

// ---------- qs GEMM: qs[bh][t][swz j] = sum_k S[t][k] * Qt[j][k] ----------
__global__ __launch_bounds__(256) void k_gemm_qs(const short* __restrict__ S, const short* __restrict__ W, short* __restrict__ C){
  __shared__ short At[128*64];
  __shared__ short Bt[128*64];
  int bh = blockIdx.y, b = bh >> 3, h = bh & 7;
  const short* A = S + (size_t)b*262144;
  const short* Bm = W + h*65536;
  short* Co = C + (size_t)bh*262144;
  int mt = blockIdx.x >> 1, nt = blockIdx.x & 1;
  int Mb = mt*128, Nb = nt*128;
  int tid = threadIdx.x, lane = tid & 63, wv = tid >> 6;
  int wm = wv >> 1, wn = wv & 1;
  int g = lane >> 4, r16 = lane & 15;
  f32x4 acc[4][4] = {};
  for (int kk = 0; kk < 4; kk++){
    __syncthreads();
    for (int c = tid; c < 1024; c += 256){
      int row = c >> 3, slot = c & 7;
      int ss = slot ^ (row & 7);
      *reinterpret_cast<i32x4*>(At + row*64 + ss*8) =
        *reinterpret_cast<const i32x4*>(A + (Mb+row)*256 + kk*64 + slot*8);
      *reinterpret_cast<i32x4*>(Bt + row*64 + ss*8) =
        *reinterpret_cast<const i32x4*>(Bm + (Nb+row)*256 + kk*64 + slot*8);
    }
    __syncthreads();
#pragma unroll
    for (int ks = 0; ks < 2; ks++){
      int slot = ks*4 + g;
      bf16x8 af[4], bf_[4];
#pragma unroll
      for (int fm = 0; fm < 4; fm++){
        int row = wm*64 + fm*16 + r16;
        af[fm] = *reinterpret_cast<const bf16x8*>(At + row*64 + (slot ^ (row & 7))*8);
      }
#pragma unroll
      for (int fn = 0; fn < 4; fn++){
        int row = wn*64 + fn*16 + r16;
        bf_[fn] = *reinterpret_cast<const bf16x8*>(Bt + row*64 + (slot ^ (row & 7))*8);
      }
#pragma unroll
      for (int fm = 0; fm < 4; fm++)
#pragma unroll
        for (int fn = 0; fn < 4; fn++)
          acc[fm][fn] = __builtin_amdgcn_mfma_f32_16x16x32_bf16(af[fm], bf_[fn], acc[fm][fn], 0, 0, 0);
    }
  }
#pragma unroll
  for (int fm = 0; fm < 4; fm++)
#pragma unroll
    for (int fn = 0; fn < 4; fn++)
#pragma unroll
      for (int rg = 0; rg < 4; rg++){
        int m = Mb + wm*64 + fm*16 + g*4 + rg;
        int n = Nb + wn*64 + fn*16 + r16;
        Co[m*256 + (((n>>3) ^ (m&7)) << 3) + (n&7)] = f2bf(acc[fm][fn][rg]);
      }
}

// ---------- phase 2: G[bh][t][j] = sum_{u<=t} Omega[t][u] * S[u][j] (bf16, swz-64 out) ----------
// grid 512: b(8) x pair(8) x h(8); 4 waves = (t-half 32) x (j-half 128)
__global__ __launch_bounds__(256, 2) void k_attn(const short* __restrict__ Ss, const short* __restrict__ Sp,
                                                 const short* __restrict__ qs, short* __restrict__ G){
  __shared__ short st[2][8192];   // [u'][swz j] 16KB each
  __shared__ short sp[2][8192];   // [j][swz u'] 16KB each
  int bI = blockIdx.x >> 6, p = (blockIdx.x >> 3) & 7, h = blockIdx.x & 7;
  int tid = threadIdx.x, lane = tid & 63, w = tid >> 6;
  int g = lane >> 4, r16 = lane & 15;
  int tw = w >> 1, jw = w & 1;
  int bh = bI*8 + h;
  const short* Sb = Ss + (size_t)bI*262144;
  const short* Tb = Sp + (size_t)bI*262144;
  int so = w*2048 + lane*8;     // per-lane src offset within a 16KB chunk (shorts)
  int dofs = w*2048;            // wave-uniform LDS dest base (shorts)

  for (int pass = 0; pass < 2; pass++){
    int T = pass ? (15 - p) : p;            // pair (p,15-p): 36 iters/block uniform
    int tbase = T*64 + tw*32;
    const short* qp = qs + ((size_t)bh*1024 + tbase)*256;
    bf16x8 Qr[2][8];
#pragma unroll
    for (int ts = 0; ts < 2; ts++)
#pragma unroll
      for (int ks = 0; ks < 8; ks++)
        Qr[ts][ks] = *reinterpret_cast<const bf16x8*>(qp + (ts*16 + r16)*256 + (((ks*4+g) ^ (r16&7)) << 3));
    int nut = 2*T + 2;
#pragma unroll
    for (int k = 0; k < 4; k++){            // stage tile 0 -> buf 0
      gll16(Sb + so + k*512, &st[0][dofs + k*512]);
      gll16(Tb + so + k*512, &sp[0][dofs + k*512]);
    }
    __syncthreads();
    f32x4 racc[2][8] = {};
    int cur = 0;
    for (int ut = 0; ut < nut; ut++){
      if (ut + 1 < nut){                    // stage next tile -> other buf
        const short* s1 = Sb + (size_t)(ut+1)*8192 + so;
        const short* t1 = Tb + (size_t)(ut+1)*8192 + so;
        int nb = cur ^ 1;
#pragma unroll
        for (int k = 0; k < 4; k++){
          gll16(s1 + k*512, &st[nb][dofs + k*512]);
          gll16(t1 + k*512, &sp[nb][dofs + k*512]);
        }
      }
      // QK: Omega^T frags, rows u, cols t
      f32x4 om[2][2] = {};                  // [ts][us]
      const short* stc = st[cur];
      __builtin_amdgcn_s_setprio(1);
#pragma unroll
      for (int ks = 0; ks < 8; ks++){
        int sl = ks*4 + g;
        bf16x8 a0 = *reinterpret_cast<const bf16x8*>(stc + r16*256 + ((sl ^ (r16&7)) << 3));
        bf16x8 a1 = *reinterpret_cast<const bf16x8*>(stc + (16+r16)*256 + ((sl ^ (r16&7)) << 3));
        om[0][0] = __builtin_amdgcn_mfma_f32_16x16x32_bf16(a0, Qr[0][ks], om[0][0], 0, 0, 0);
        om[0][1] = __builtin_amdgcn_mfma_f32_16x16x32_bf16(a1, Qr[0][ks], om[0][1], 0, 0, 0);
        om[1][0] = __builtin_amdgcn_mfma_f32_16x16x32_bf16(a0, Qr[1][ks], om[1][0], 0, 0, 0);
        om[1][1] = __builtin_amdgcn_mfma_f32_16x16x32_bf16(a1, Qr[1][ks], om[1][1], 0, 0, 0);
      }
      __builtin_amdgcn_s_setprio(0);
      // mask (lane-local) + repack: PA is an exact standard A-fragment
      bf16x8 PA[2];
      int ub = ut*32;
#pragma unroll
      for (int ts = 0; ts < 2; ts++){
        int tl = tbase + ts*16 + r16;
#pragma unroll
        for (int us = 0; us < 2; us++)
#pragma unroll
          for (int rg = 0; rg < 4; rg++){
            int u = ub + us*16 + g*4 + rg;
            float v = (u <= tl) ? om[ts][us][rg] : 0.0f;
            PA[ts][us*4+rg] = f2bf(v);
          }
      }
      // PV: G += Omega * S_u  (B = S^T u-chunk, true k-layout slots g / 4+g)
      const short* spc = sp[cur];
      __builtin_amdgcn_s_setprio(1);
#pragma unroll
      for (int n = 0; n < 8; n++){
        int jr = jw*128 + n*16 + r16;
        s16x4 lo = *reinterpret_cast<const s16x4*>(spc + jr*32 + ((g ^ (r16&7)) << 2));
        s16x4 hi = *reinterpret_cast<const s16x4*>(spc + jr*32 + (((4+g) ^ (r16&7)) << 2));
        bf16x8 be;
        be[0]=lo[0]; be[1]=lo[1]; be[2]=lo[2]; be[3]=lo[3];
        be[4]=hi[0]; be[5]=hi[1]; be[6]=hi[2]; be[7]=hi[3];
        racc[0][n] = __builtin_amdgcn_mfma_f32_16x16x32_bf16(PA[0], be, racc[0][n], 0, 0, 0);
        racc[1][n] = __builtin_amdgcn_mfma_f32_16x16x32_bf16(PA[1], be, racc[1][n], 0, 0, 0);
      }
      __builtin_amdgcn_s_setprio(0);
      __syncthreads();
      cur ^= 1;
    }
    // epilogue: G bf16, pre-swizzled per 64-col block for k_out's A staging
    short* Gp = G + (size_t)bh*262144;
#pragma unroll
    for (int ts = 0; ts < 2; ts++)
#pragma unroll
      for (int rg = 0; rg < 4; rg++){
        int t = tbase + ts*16 + g*4 + rg;
#pragma unroll
        for (int n = 0; n < 8; n++){
          int j = jw*128 + n*16 + r16;
          int pos = (j>>6)*64 + ((((j>>3)&7) ^ (t&7)) << 3) + (j&7);
          Gp[t*256 + pos] = f2bf(racc[ts][n][rg]);
        }
      }
  }
}

// ---------- phase 3: out[b][t][i] = sum_{h,j} G[bh][t][j] * E[h][i][j]  (K=2048) ----------
// grid 512: b(8) x mt(16, 64t) x nt(4, 64i); 4 waves = 2x2 of 32x32
__global__ __launch_bounds__(256) void k_out(const short* __restrict__ G, const short* __restrict__ E,
                                             float* __restrict__ out){
  __shared__ short At[2][4096];
  __shared__ short Bt[2][4096];
  int bid = blockIdx.x;
  int bI = bid >> 6, mt = (bid >> 2) & 15, nt = bid & 3;
  int Mb = mt*64, Nb = nt*64;
  int tid = threadIdx.x, lane = tid & 63, w = tid >> 6;
  int g = lane >> 4, r16 = lane & 15;
  int wm = w >> 1, wn = w & 1;
  const short* Gb = G + (size_t)bI*8*262144;
  int arow = w*16 + (lane >> 3);   // + ia*8
  int acol = (lane & 7) * 8;
  f32x4 acc[2][2] = {};
  // prologue: stage kk=0
  {
    const short* Ah = Gb + (size_t)Mb*256;
    const short* Bh = E + (size_t)Nb*256;
#pragma unroll
    for (int ia = 0; ia < 2; ia++){
      gll16(Ah + (arow + ia*8)*256 + acol, &At[0][(w*2+ia)*512]);
      gll16(Bh + (arow + ia*8)*256 + acol, &Bt[0][(w*2+ia)*512]);
    }
  }
  __syncthreads();
  int cur = 0;
  for (int kk = 0; kk < 32; kk++){
    if (kk + 1 < 32){
      int h = (kk+1) >> 2, jb = ((kk+1) & 3) * 64;
      const short* Ah = Gb + (size_t)h*262144 + (size_t)Mb*256 + jb;
      const short* Bh = E + (size_t)h*65536 + (size_t)Nb*256 + jb;
      int nb = cur ^ 1;
#pragma unroll
      for (int ia = 0; ia < 2; ia++){
        gll16(Ah + (arow + ia*8)*256 + acol, &At[nb][(w*2+ia)*512]);
        gll16(Bh + (arow + ia*8)*256 + acol, &Bt[nb][(w*2+ia)*512]);
      }
    }
    const short* Ac = At[cur];
    const short* Bc = Bt[cur];
    __builtin_amdgcn_s_setprio(1);
#pragma unroll
    for (int ks = 0; ks < 2; ks++){
      bf16x8 af[2], bf_[2];
#pragma unroll
      for (int ms = 0; ms < 2; ms++){
        int row = wm*32 + ms*16 + r16;
        af[ms] = *reinterpret_cast<const bf16x8*>(Ac + row*64 + (((ks*4+g) ^ (row&7)) << 3));
      }
#pragma unroll
      for (int ns = 0; ns < 2; ns++){
        int row = wn*32 + ns*16 + r16;
        bf_[ns] = *reinterpret_cast<const bf16x8*>(Bc + row*64 + (((ks*4+g) ^ (row&7)) << 3));
      }
#pragma unroll
      for (int ms = 0; ms < 2; ms++)
#pragma unroll
        for (int ns = 0; ns < 2; ns++)
          acc[ms][ns] = __builtin_amdgcn_mfma_f32_16x16x32_bf16(af[ms], bf_[ns], acc[ms][ns], 0, 0, 0);
    }
    __builtin_amdgcn_s_setprio(0);
    __syncthreads();
    cur ^= 1;
  }
  float* ob = out + (size_t)bI*262144;
#pragma unroll
  for (int ms = 0; ms < 2; ms++)
#pragma unroll
    for (int ns = 0; ns < 2; ns++)
#pragma unroll
      for (int rg = 0; rg < 4; rg++)
        ob[(Mb + wm*32 + ms*16 + g*4 + rg)*256 + Nb + wn*32 + ns*16 + r16] = acc[ms][ns][rg];
}

extern "C" void kernel_launch(void* const* d_in, const int* in_sizes, int n_in,
                              void* d_out, int out_size, void* d_ws, size_t ws_size,
                              hipStream_t stream){
  (void)in_sizes; (void)n_in; (void)out_size; (void)ws_size;
  const float* s = (const float*)d_in[0];
  const float* Q = (const float*)d_in[1];
  const float* E = (const float*)d_in[2];
  float* out = (float*)d_out;
  char* ws = (char*)d_ws;
  // ws: S16 4MB | S16s 4MB | Stc 4MB | E16s 1MB | Qt 1MB | qs 32MB | G 32MB = 78MB
  short* S16  = (short*)(ws);
  short* S16s = (short*)(ws + 4194304);
  short* Stc  = (short*)(ws + 8388608);
  short* E16s = (short*)(ws + 12582912);
  short* Qt   = (short*)(ws + 13631488);
  short* qsb  = (short*)(ws + 14680064);
  short* G    = (short*)(ws + 48234496);

  k_cvt_s<<<1024, 256, 0, stream>>>(s, S16, S16s);
  k_st   <<<256,  256, 0, stream>>>(s, Stc);
  k_cvtE <<<512,  256, 0, stream>>>(E, E16s);
  k_qt   <<<512,  256, 0, stream>>>(Q, Qt);
  k_gemm_qs<<<dim3(16, 64), 256, 0, stream>>>(S16, Qt, qsb);
  k_attn <<<512, 256, 0, stream>>>(S16s, Stc, qsb, G);
  k_out  <<<512, 256, 0, stream>>>(G, E16s, out);
}